// Round 13
// baseline (277.273 us; speedup 1.0000x reference)
//
#include <hip/hip_runtime.h>
#include <hip/hip_bf16.h>

#define NN 100000
#define NE 1280000
#define DD 64
#define RSHIFT 9             // 512-node dst ranges
#define NRANGE 196           // ceil(NN/512)
#define NPAD (NRANGE * 512)  // 100352
#define RCAP 8192            // fixed edge-slot capacity per range (mean 6554, 20 sigma)
#define RPSTRIDE 513         // rowp stride per range (512 cursors + end sentinel)

typedef __attribute__((ext_vector_type(8))) short bf16x8;
typedef __attribute__((ext_vector_type(4))) float f32x4;

static __device__ __forceinline__ unsigned short f2bf(float f) {
    __hip_bfloat16 h = __float2bfloat16(f);
    return *reinterpret_cast<unsigned short*>(&h);
}

// ---------------------------------------------------------------------------
// x (fp32) -> bf16 copy. Grid 6250 x 256, 4 elems/thread (exact: 6.4M).
// ---------------------------------------------------------------------------
__global__ __launch_bounds__(256) void f32_to_bf16_kernel(
    const float* __restrict__ in, unsigned short* __restrict__ out)
{
    int i = (blockIdx.x * 256 + threadIdx.x) * 4;
    float4 v = *(const float4*)(in + i);
    ushort4 o;
    o.x = f2bf(v.x); o.y = f2bf(v.y); o.z = f2bf(v.z); o.w = f2bf(v.w);
    *(ushort4*)(out + i) = o;
}

// ---------------------------------------------------------------------------
// B-fragment pre-pack (blocks 0-2) + gcur fixed-base init (block 3). Grid 4.
// ---------------------------------------------------------------------------
__global__ __launch_bounds__(256) void bpack_kernel(
    const float* __restrict__ Wrel1, const float* __restrict__ Wroot1,
    const float* __restrict__ Wrel2, const float* __restrict__ Wroot2,
    const float* __restrict__ Wrel3, const float* __restrict__ Wroot3,
    unsigned short* __restrict__ Bp, int* __restrict__ gcur)
{
    int L = blockIdx.x;
    int tid = threadIdx.x;
    if (L == 3) {                         // gcur[r] = r*RCAP
        if (tid < NRANGE) gcur[tid] = tid * RCAP;
        return;
    }
    const float* Wrel  = (L == 0) ? Wrel1  : (L == 1) ? Wrel2  : Wrel3;
    const float* Wroot = (L == 0) ? Wroot1 : (L == 1) ? Wroot2 : Wroot3;
    int wv = tid >> 6, lane = tid & 63, quad = lane >> 4, m16 = lane & 15;
    int n = wv * 16 + m16;
    unsigned short* o = Bp + (size_t)L * 4 * 256 * 8;
#pragma unroll
    for (int t = 0; t < 4; ++t)
#pragma unroll
        for (int j = 0; j < 8; ++j) {
            int k = t * 32 + quad * 8 + j;
            float wval = (k < 64) ? Wrel[k * 64 + n] : Wroot[(k - 64) * 64 + n];
            o[((size_t)t * 256 + tid) * 8 + j] = f2bf(wval);
        }
}

// ---------------------------------------------------------------------------
// P1: bin edges by 512-node dst range into FIXED-CAPACITY segments.
// 512 thr, 4 edges/thr (2048-edge chunks, grid 625), wave-shfl scan over
// 196 bins. Record: src(17b)|local-dst(9b@17).
// ---------------------------------------------------------------------------
__global__ __launch_bounds__(512) void p1_bin_kernel(
    const int* __restrict__ src, const int* __restrict__ dst,
    const float* __restrict__ w, int* __restrict__ gcur,
    int2* __restrict__ ecoarse)
{
    __shared__ int2 stage[2048];                 // 16 KB
    __shared__ unsigned char sbkt[2048];         // 2 KB
    __shared__ int cnt[NRANGE], ofs[NRANGE], gpos[NRANGE];
    __shared__ int wsum[4];

    int tid = threadIdx.x;
    int e0 = blockIdx.x * 2048 + tid * 4;
    int4   s4 = *(const int4*)(src + e0);
    int4   d4 = *(const int4*)(dst + e0);
    float4 w4 = *(const float4*)(w + e0);

    if (tid < NRANGE) cnt[tid] = 0;
    __syncthreads();

    int ss[4] = {s4.x, s4.y, s4.z, s4.w};
    int dd[4] = {d4.x, d4.y, d4.z, d4.w};
    float ww[4] = {w4.x, w4.y, w4.z, w4.w};
    int b[4], p[4];
#pragma unroll
    for (int i = 0; i < 4; ++i) {
        b[i] = dd[i] >> RSHIFT;
        p[i] = atomicAdd(&cnt[b[i]], 1);
    }
    __syncthreads();

    int sum = 0, v = 0;
    if (tid < NRANGE) {
        v = cnt[tid];
        int lane6 = tid & 63;
        sum = v;
#pragma unroll
        for (int o = 1; o < 64; o <<= 1) {
            int t = __shfl_up(sum, o);
            if (lane6 >= o) sum += t;
        }
        if (lane6 == 63 || tid == NRANGE - 1) wsum[tid >> 6] = sum;
        ofs[tid] = sum - v;
    }
    __syncthreads();
    if (tid < NRANGE) {
        int wid = tid >> 6;
        int pre = 0;
#pragma unroll
        for (int k = 0; k < 3; ++k) pre += (k < wid) ? wsum[k] : 0;
        ofs[tid] += pre;
        if (v > 0) gpos[tid] = atomicAdd(&gcur[tid], v);
    }
    __syncthreads();

#pragma unroll
    for (int i = 0; i < 4; ++i) {
        int slot = ofs[b[i]] + p[i];
        stage[slot] = make_int2(ss[i] | ((dd[i] & 511) << 17), __float_as_int(ww[i]));
        sbkt[slot] = (unsigned char)b[i];
    }
    __syncthreads();

#pragma unroll
    for (int u = 0; u < 4; ++u) {
        int j = tid + u * 512;
        int bb = sbkt[j];
        ecoarse[gpos[bb] + (j - ofs[bb])] = stage[j];
    }
}

// ---------------------------------------------------------------------------
// P2: per-range count + wave-shfl scan -> rowp (stride-513, end sentinel) +
// cursors, then place. Grid NRANGE(196) x 1024 thr. beg = r*RCAP (fixed),
// end = gcur[r] (from p1). Final ebuf record: { src*128 (byte offset), w }.
// ---------------------------------------------------------------------------
__global__ __launch_bounds__(1024) void p2_place_kernel(
    const int2* __restrict__ ecoarse, const int* __restrict__ gcur,
    int* __restrict__ rowp, int2* __restrict__ ebuf)
{
    __shared__ int cnt[512];
    __shared__ int wsum[8];
    int r = blockIdx.x, tid = threadIdx.x;
    int beg = r * RCAP;
    int end = gcur[r];

    if (tid < 512) cnt[tid] = 0;
    __syncthreads();

    for (int j = beg + tid; j < end; j += 1024) {
        int2 rec = ecoarse[j];
        atomicAdd(&cnt[(rec.x >> 17) & 511], 1);
    }
    __syncthreads();

    int v = 0, sum = 0;
    if (tid < 512) {
        v = cnt[tid]; sum = v;
        int lane6 = tid & 63;
#pragma unroll
        for (int o = 1; o < 64; o <<= 1) {
            int t = __shfl_up(sum, o);
            if (lane6 >= o) sum += t;
        }
        if (lane6 == 63) wsum[tid >> 6] = sum;
    }
    __syncthreads();
    if (tid < 512) {
        int wid = tid >> 6;
        int pre = 0;
#pragma unroll
        for (int k = 0; k < 7; ++k) pre += (k < wid) ? wsum[k] : 0;
        int ex = beg + pre + sum - v;       // exclusive cursor for local node tid
        rowp[r * RPSTRIDE + tid] = ex;
        cnt[tid] = ex;
    }
    if (tid == 0) rowp[r * RPSTRIDE + 512] = end;   // range end sentinel
    __syncthreads();

    for (int j = beg + tid; j < end; j += 1024) {
        int2 rec = ecoarse[j];
        int dl = (rec.x >> 17) & 511;
        int pp = atomicAdd(&cnt[dl], 1);
        ebuf[pp] = make_int2((rec.x & 0x1FFFF) << 7, rec.y);   // src*128 bytes
    }
}

// ---------------------------------------------------------------------------
// FUSED layer (2-TILE): CSR gather + dual GEMM + bias (+ReLU). Block =
// 512 thr = 8 waves = 32 nodes (TWO MFMA m-tiles). Each half-wave owns one
// node of tile 0 AND one of tile 1 -> two independent gather chains, 2 ebuf
// stages in flight, 32 row loads in flight/wave (2x the 1-tile version,
// which was latency-chain-bound at occupancy 33%/VALU 34%). Records staged
// to per-wave dual LDS slabs (pad slots w=0 at stage time); streamed via
// half-uniform ds_read_b64. Row addr = pre-scaled byte offset + ch*4.
// GEMM: all 8 waves (0-3 -> tile0, 4-7 -> tile1); agg k0..63 via 4 KB AstW;
// root k64..127 loaded directly from hb (r12-verified fragment mapping:
// kstep t2 in {2,3} = 16 B of row (tileBase+m16) at byte (t2-2)*64+quad*16).
// rowp stride-513 per range: idx = node + (node>>9).
// ---------------------------------------------------------------------------
template <bool RELU, bool OUT32>
__global__ __launch_bounds__(512) void fused_layer_kernel(
    const unsigned short* __restrict__ hb,   // input node table (gather + root)
    const int* __restrict__ rowp,
    const int2* __restrict__ ebuf,
    const unsigned short* __restrict__ Bp,   // [4][256][8] bf16 (this layer)
    const float* __restrict__ brel,
    void* __restrict__ outp)
{
    __shared__ __align__(16) unsigned int AstW[4 * 256];   // 4 KB: 2 tiles x 2 ksteps
    __shared__ __align__(16) int2 seW[8][2][64];           // 8 KB per-wave dual slabs

    int tid = threadIdx.x;
    int lane = tid & 63;
    int wv = tid >> 6;            // 0..7
    int half = lane >> 5;
    int ch = lane & 31;           // channel pair
    int base = blockIdx.x * 32;
    int m = wv * 2 + half;        // row within tile, 0..15
    int nodeA = base + m;         // tile 0 node
    int nodeB = base + 16 + m;    // tile 1 node
    int rr = base >> 9;           // range id (uniform; block fully in-range)

    const char* __restrict__ hbase = (const char*)hb;
    unsigned chB = (unsigned)ch * 4;

    // GEMM role: tile ti = wv>>2, quadrant-wave wv4 = wv&3
    int ti = wv >> 2, wv4 = wv & 3;
    int quad = lane >> 4, m16 = lane & 15;

    // B fragments + bias + direct root fragments (all 8 waves GEMM now)
    bf16x8 bfrag[4];
#pragma unroll
    for (int t2 = 0; t2 < 4; ++t2)
        bfrag[t2] = *(const bf16x8*)(Bp + ((size_t)t2 * 256 + (tid & 255)) * 8);
    float bias = brel[(wv4 << 4) | m16];
    const char* rrow = hbase + (size_t)(base + ti * 16 + m16) * 128 + quad * 16;
    bf16x8 aroot0 = *(const bf16x8*)(rrow);
    bf16x8 aroot1 = *(const bf16x8*)(rrow + 64);

    int begA = rowp[nodeA + rr];
    int degA = rowp[nodeA + rr + 1] - begA;
    int begB = rowp[nodeB + rr];
    int degB = rowp[nodeB + rr + 1] - begB;
    int dM = degA > degB ? degA : degB;

    float aLA[4] = {0.f,0.f,0.f,0.f}, aHA[4] = {0.f,0.f,0.f,0.f};
    float aLB[4] = {0.f,0.f,0.f,0.f}, aHB[4] = {0.f,0.f,0.f,0.f};

    for (int c = 0; c < dM; c += 32) {
        // stage both chunks (independent loads; pad slots w=0, clamped idx)
        {
            int j = c + ch;
            int ja = j < degA ? j : (degA - 1); if (ja < 0) ja = 0;
            int jb = j < degB ? j : (degB - 1); if (jb < 0) jb = 0;
            int2 eA = ebuf[begA + ja];
            int2 eB = ebuf[begB + jb];
            if (j >= degA) eA.y = 0;
            if (j >= degB) eB.y = 0;
            seW[wv][0][half * 32 + ch] = eA;
            seW[wv][1][half * 32 + ch] = eB;
        }
        int nsl = dM - c; if (nsl > 32) nsl = 32;
        for (int s0 = 0; s0 < nsl; s0 += 16) {
#pragma unroll
            for (int i = 0; i < 16; ++i) {
                int2 rA = seW[wv][0][half * 32 + s0 + i];   // broadcast ds_read_b64
                int2 rB = seW[wv][1][half * 32 + s0 + i];
                float wA = __int_as_float(rA.y);
                float wB = __int_as_float(rB.y);
                unsigned vA = *(const unsigned*)(hbase + ((unsigned)rA.x + chB));
                unsigned vB = *(const unsigned*)(hbase + ((unsigned)rB.x + chB));
                aLA[i & 3] = fmaf(wA, __uint_as_float(vA << 16), aLA[i & 3]);
                aHA[i & 3] = fmaf(wA, __uint_as_float(vA & 0xFFFF0000u), aHA[i & 3]);
                aLB[i & 3] = fmaf(wB, __uint_as_float(vB << 16), aLB[i & 3]);
                aHB[i & 3] = fmaf(wB, __uint_as_float(vB & 0xFFFF0000u), aHB[i & 3]);
            }
        }
    }
    float accLA = (aLA[0] + aLA[1]) + (aLA[2] + aLA[3]);
    float accHA = (aHA[0] + aHA[1]) + (aHA[2] + aHA[3]);
    float accLB = (aLB[0] + aLB[1]) + (aLB[2] + aLB[3]);
    float accHB = (aHB[0] + aHB[1]) + (aHB[2] + aHB[3]);

    // stage agg pairs (k 0..63) for both tiles in fragment order
    int t = ch >> 4, q = (ch >> 2) & 3, jj = ch & 3;
    unsigned packA = ((unsigned)f2bf(accHA) << 16) | (unsigned)f2bf(accLA);
    unsigned packB = ((unsigned)f2bf(accHB) << 16) | (unsigned)f2bf(accLB);
    AstW[t * 256 + (q * 16 + m) * 4 + jj] = packA;
    AstW[512 + t * 256 + (q * 16 + m) * 4 + jj] = packB;
    __syncthreads();

    {
        int n = wv4 * 16 + m16;
        f32x4 cacc = {0.f, 0.f, 0.f, 0.f};
#pragma unroll
        for (int t2 = 0; t2 < 2; ++t2) {
            bf16x8 a = *(const bf16x8*)&AstW[ti * 512 + t2 * 256 + lane * 4];
            cacc = __builtin_amdgcn_mfma_f32_16x16x32_bf16(a, bfrag[t2], cacc, 0, 0, 0);
        }
        cacc = __builtin_amdgcn_mfma_f32_16x16x32_bf16(aroot0, bfrag[2], cacc, 0, 0, 0);
        cacc = __builtin_amdgcn_mfma_f32_16x16x32_bf16(aroot1, bfrag[3], cacc, 0, 0, 0);
#pragma unroll
        for (int reg = 0; reg < 4; ++reg) {
            int row = quad * 4 + reg;
            size_t onode = (size_t)base + ti * 16 + row;
            float v2 = cacc[reg] + bias;
            if (RELU) v2 = fmaxf(v2, 0.f);
            if (OUT32) ((float*)outp)[onode * DD + n] = v2;
            else       ((unsigned short*)outp)[onode * DD + n] = f2bf(v2);
        }
    }
}

extern "C" void kernel_launch(void* const* d_in, const int* in_sizes, int n_in,
                              void* d_out, int out_size, void* d_ws, size_t ws_size,
                              hipStream_t stream)
{
    const float* x     = (const float*)d_in[0];
    const int*   ei    = (const int*)d_in[1];
    const float* w     = (const float*)d_in[2];
    const float* Wrel1 = (const float*)d_in[4];
    const float* brel1 = (const float*)d_in[5];
    const float* Wroot1= (const float*)d_in[6];
    const float* Wrel2 = (const float*)d_in[7];
    const float* brel2 = (const float*)d_in[8];
    const float* Wroot2= (const float*)d_in[9];
    const float* Wrel3 = (const float*)d_in[10];
    const float* brel3 = (const float*)d_in[11];
    const float* Wroot3= (const float*)d_in[12];

    float* out = (float*)d_out;

    // workspace: ebuf | ecoarse->xb alias | hb1 | hb2 | rowp | gcur | Bp
    char* ws = (char*)d_ws;
    int2*  ebuf    = (int2*)ws;                ws += (size_t)NRANGE * RCAP * 8;  // 12.85 MB
    int2*  ecoarse = (int2*)ws;                                                 // aliases xb
    unsigned short* xb  = (unsigned short*)ws; ws += (size_t)NRANGE * RCAP * 8;  // 12.85 MB (>= xb)
    unsigned short* hb1 = (unsigned short*)ws; ws += (size_t)NPAD * DD * 2;
    unsigned short* hb2 = (unsigned short*)ws; ws += (size_t)NPAD * DD * 2;
    int*   rowp  = (int*)ws;                   ws += (size_t)(NRANGE * RPSTRIDE + 16) * 4;
    int*   gcur  = (int*)ws;                   ws += (size_t)256 * 4;
    unsigned short* Bp = (unsigned short*)ws;  // 3 * 16 KB

    const int* src = ei;
    const int* dst = ei + NE;

    // ---- build: gcur init (bpack blk 3) -> bin -> place (no hist/scan) ----
    bpack_kernel<<<4, 256, 0, stream>>>(Wrel1, Wroot1, Wrel2, Wroot2,
                                        Wrel3, Wroot3, Bp, gcur);
    p1_bin_kernel<<<625, 512, 0, stream>>>(src, dst, w, gcur, ecoarse);
    p2_place_kernel<<<NRANGE, 1024, 0, stream>>>(ecoarse, gcur, rowp, ebuf);

    // ---- xb = bf16(x) (ecoarse dead now) ----
    f32_to_bf16_kernel<<<6250, 256, 0, stream>>>(x, xb);

    // ---- 3 fused 2-tile layers (ping-pong xb -> hb1 -> hb2 -> out) ----
    fused_layer_kernel<true, false><<<NN / 32, 512, 0, stream>>>(
        xb, rowp, ebuf, Bp, brel1, hb1);
    fused_layer_kernel<true, false><<<NN / 32, 512, 0, stream>>>(
        hb1, rowp, ebuf, Bp + (size_t)4 * 256 * 8, brel2, hb2);
    fused_layer_kernel<false, true><<<NN / 32, 512, 0, stream>>>(
        hb2, rowp, ebuf, Bp + (size_t)8 * 256 * 8, brel3, out);
}

// Round 14
// 256.852 us; speedup vs baseline: 1.0795x; 1.0795x over previous
//
#include <hip/hip_runtime.h>
#include <hip/hip_bf16.h>

#define NN 100000
#define NE 1280000
#define DD 64
#define RSHIFT 9             // 512-node dst ranges
#define NRANGE 196           // ceil(NN/512)
#define NPAD (NRANGE * 512)  // 100352
#define RCAP 8192            // fixed edge-slot capacity per range (mean 6554, 20 sigma)
#define RPSTRIDE 513         // rowp stride per range (512 cursors + end sentinel)
#define CPBLK 1563           // copy blocks in p2copy (4096 floats each)

typedef __attribute__((ext_vector_type(8))) short bf16x8;
typedef __attribute__((ext_vector_type(4))) float f32x4;

static __device__ __forceinline__ unsigned short f2bf(float f) {
    __hip_bfloat16 h = __float2bfloat16(f);
    return *reinterpret_cast<unsigned short*>(&h);
}

// ---------------------------------------------------------------------------
// B-fragment pre-pack (blocks 0-2) + gcur fixed-base init (block 3). Grid 4.
// ---------------------------------------------------------------------------
__global__ __launch_bounds__(256) void bpack_kernel(
    const float* __restrict__ Wrel1, const float* __restrict__ Wroot1,
    const float* __restrict__ Wrel2, const float* __restrict__ Wroot2,
    const float* __restrict__ Wrel3, const float* __restrict__ Wroot3,
    unsigned short* __restrict__ Bp, int* __restrict__ gcur)
{
    int L = blockIdx.x;
    int tid = threadIdx.x;
    if (L == 3) {                         // gcur[r] = r*RCAP
        if (tid < NRANGE) gcur[tid] = tid * RCAP;
        return;
    }
    const float* Wrel  = (L == 0) ? Wrel1  : (L == 1) ? Wrel2  : Wrel3;
    const float* Wroot = (L == 0) ? Wroot1 : (L == 1) ? Wroot2 : Wroot3;
    int wv = tid >> 6, lane = tid & 63, quad = lane >> 4, m16 = lane & 15;
    int n = wv * 16 + m16;
    unsigned short* o = Bp + (size_t)L * 4 * 256 * 8;
#pragma unroll
    for (int t = 0; t < 4; ++t)
#pragma unroll
        for (int j = 0; j < 8; ++j) {
            int k = t * 32 + quad * 8 + j;
            float wval = (k < 64) ? Wrel[k * 64 + n] : Wroot[(k - 64) * 64 + n];
            o[((size_t)t * 256 + tid) * 8 + j] = f2bf(wval);
        }
}

// ---------------------------------------------------------------------------
// P1: bin edges by 512-node dst range into FIXED-CAPACITY segments.
// 512 thr, 4 edges/thr (2048-edge chunks, grid 625), wave-shfl scan over
// 196 bins. Record: src(17b)|local-dst(9b@17).
// ---------------------------------------------------------------------------
__global__ __launch_bounds__(512) void p1_bin_kernel(
    const int* __restrict__ src, const int* __restrict__ dst,
    const float* __restrict__ w, int* __restrict__ gcur,
    int2* __restrict__ ecoarse)
{
    __shared__ int2 stage[2048];                 // 16 KB
    __shared__ unsigned char sbkt[2048];         // 2 KB
    __shared__ int cnt[NRANGE], ofs[NRANGE], gpos[NRANGE];
    __shared__ int wsum[4];

    int tid = threadIdx.x;
    int e0 = blockIdx.x * 2048 + tid * 4;
    int4   s4 = *(const int4*)(src + e0);
    int4   d4 = *(const int4*)(dst + e0);
    float4 w4 = *(const float4*)(w + e0);

    if (tid < NRANGE) cnt[tid] = 0;
    __syncthreads();

    int ss[4] = {s4.x, s4.y, s4.z, s4.w};
    int dd[4] = {d4.x, d4.y, d4.z, d4.w};
    float ww[4] = {w4.x, w4.y, w4.z, w4.w};
    int b[4], p[4];
#pragma unroll
    for (int i = 0; i < 4; ++i) {
        b[i] = dd[i] >> RSHIFT;
        p[i] = atomicAdd(&cnt[b[i]], 1);
    }
    __syncthreads();

    int sum = 0, v = 0;
    if (tid < NRANGE) {
        v = cnt[tid];
        int lane6 = tid & 63;
        sum = v;
#pragma unroll
        for (int o = 1; o < 64; o <<= 1) {
            int t = __shfl_up(sum, o);
            if (lane6 >= o) sum += t;
        }
        if (lane6 == 63 || tid == NRANGE - 1) wsum[tid >> 6] = sum;
        ofs[tid] = sum - v;
    }
    __syncthreads();
    if (tid < NRANGE) {
        int wid = tid >> 6;
        int pre = 0;
#pragma unroll
        for (int k = 0; k < 3; ++k) pre += (k < wid) ? wsum[k] : 0;
        ofs[tid] += pre;
        if (v > 0) gpos[tid] = atomicAdd(&gcur[tid], v);
    }
    __syncthreads();

#pragma unroll
    for (int i = 0; i < 4; ++i) {
        int slot = ofs[b[i]] + p[i];
        stage[slot] = make_int2(ss[i] | ((dd[i] & 511) << 17), __float_as_int(ww[i]));
        sbkt[slot] = (unsigned char)b[i];
    }
    __syncthreads();

#pragma unroll
    for (int u = 0; u < 4; ++u) {
        int j = tid + u * 512;
        int bb = sbkt[j];
        ecoarse[gpos[bb] + (j - ofs[bb])] = stage[j];
    }
}

// ---------------------------------------------------------------------------
// P2 + COPY combined (one dispatch, overlapped):
//   blocks 0..195   : per-range count + wave-shfl scan -> rowp (stride-513,
//                     end sentinel) + cursors, then place into ebuf.
//                     Record out: { src*128 (byte offset), w }.
//   blocks 196..1758: f32->bf16 copy of x (pure-BW work that fills the
//                     machine while p2 blocks wait on latency). Tiny LDS
//                     (2 KB) so copy-block residency is unharmed (the r12
//                     p1-merge failed because p1 carries 18 KB LDS).
// ---------------------------------------------------------------------------
__global__ __launch_bounds__(1024) void p2copy_kernel(
    const int2* __restrict__ ecoarse, const int* __restrict__ gcur,
    int* __restrict__ rowp, int2* __restrict__ ebuf,
    const float* __restrict__ xin, unsigned short* __restrict__ xb)
{
    __shared__ int cnt[512];
    __shared__ int wsum[8];
    int tid = threadIdx.x;

    if (blockIdx.x >= NRANGE) {
        // ---- copy branch: 4096 floats per block ----
        int i = ((blockIdx.x - NRANGE) * 1024 + tid) * 4;
        if (i < NN * DD) {
            float4 v = *(const float4*)(xin + i);
            ushort4 o;
            o.x = f2bf(v.x); o.y = f2bf(v.y); o.z = f2bf(v.z); o.w = f2bf(v.w);
            *(ushort4*)(xb + i) = o;
        }
        return;
    }

    int r = blockIdx.x;
    int beg = r * RCAP;
    int end = gcur[r];

    if (tid < 512) cnt[tid] = 0;
    __syncthreads();

    for (int j = beg + tid; j < end; j += 1024) {
        int2 rec = ecoarse[j];
        atomicAdd(&cnt[(rec.x >> 17) & 511], 1);
    }
    __syncthreads();

    int v = 0, sum = 0;
    if (tid < 512) {
        v = cnt[tid]; sum = v;
        int lane6 = tid & 63;
#pragma unroll
        for (int o = 1; o < 64; o <<= 1) {
            int t = __shfl_up(sum, o);
            if (lane6 >= o) sum += t;
        }
        if (lane6 == 63) wsum[tid >> 6] = sum;
    }
    __syncthreads();
    if (tid < 512) {
        int wid = tid >> 6;
        int pre = 0;
#pragma unroll
        for (int k = 0; k < 7; ++k) pre += (k < wid) ? wsum[k] : 0;
        int ex = beg + pre + sum - v;       // exclusive cursor for local node tid
        rowp[r * RPSTRIDE + tid] = ex;
        cnt[tid] = ex;
    }
    if (tid == 0) rowp[r * RPSTRIDE + 512] = end;   // range end sentinel
    __syncthreads();

    for (int j = beg + tid; j < end; j += 1024) {
        int2 rec = ecoarse[j];
        int dl = (rec.x >> 17) & 511;
        int pp = atomicAdd(&cnt[dl], 1);
        ebuf[pp] = make_int2((rec.x & 0x1FFFF) << 7, rec.y);   // src*128 bytes
    }
}

// ---------------------------------------------------------------------------
// FUSED layer (r12-verified, 41.9 us): CSR gather + dual GEMM + bias
// (+ReLU). Block = 512 thr = 8 waves = 16 nodes, half-wave per node
// (32 lanes = 32 channel pairs). Per 32-edge chunk: records staged to a
// per-wave LDS slab (pad slots w=0 at stage time), streamed via
// half-uniform ds_read_b64. Row addr = pre-scaled byte offset + ch*4;
// 16 row loads in flight/wave. AGG fragments (k 0..63) via 2 KB AstW;
// ROOT fragments (k 64..127) loaded DIRECTLY from hb (fragment mapping:
// kstep t2 in {2,3} = 16 B of row (base+m16) at byte (t2-2)*64+quad*16).
// rowp stride-513 per range: idx = node + (node>>9).
// ---------------------------------------------------------------------------
template <bool RELU, bool OUT32>
__global__ __launch_bounds__(512) void fused_layer_kernel(
    const unsigned short* __restrict__ hb,   // input node table (gather + root)
    const int* __restrict__ rowp,
    const int2* __restrict__ ebuf,
    const unsigned short* __restrict__ Bp,   // [4][256][8] bf16 (this layer)
    const float* __restrict__ brel,
    void* __restrict__ outp)
{
    __shared__ __align__(16) unsigned int AstW[2 * 256];   // 2 KB (agg only)
    __shared__ __align__(16) int2 seW[8][64];              // 4 KB per-wave slabs

    int tid = threadIdx.x;
    int lane = tid & 63;
    int wv = tid >> 6;            // 0..7
    int half = lane >> 5;         // node parity within wave
    int ch = lane & 31;           // channel pair
    int base = blockIdx.x * 16;
    int node = base + wv * 2 + half;
    int rr = base >> 9;           // range id (uniform per block)

    const char* __restrict__ hbase = (const char*)hb;
    unsigned chB = (unsigned)ch * 4;

    // B fragments + bias + DIRECT root fragments preloaded (waves 0-3 only)
    bf16x8 bfrag[4];
    bf16x8 aroot[2];
    float bias = 0.f;
    if (wv < 4) {
#pragma unroll
        for (int t2 = 0; t2 < 4; ++t2)
            bfrag[t2] = *(const bf16x8*)(Bp + ((size_t)t2 * 256 + tid) * 8);
        bias = brel[(wv << 4) | (lane & 15)];
        int quad = lane >> 4, m16 = lane & 15;
        const char* rrow = hbase + (size_t)(base + m16) * 128 + quad * 16;
        aroot[0] = *(const bf16x8*)(rrow);
        aroot[1] = *(const bf16x8*)(rrow + 64);
    }

    int beg = rowp[node + rr];
    int end = rowp[node + rr + 1];
    int deg = end - beg;

    float aL[4] = {0.f, 0.f, 0.f, 0.f};
    float aH[4] = {0.f, 0.f, 0.f, 0.f};

    for (int c = 0; c < deg; c += 32) {
        int nsl = deg - c; if (nsl > 32) nsl = 32;
        // stage chunk records; pad slots get w=0 (one select per chunk)
        {
            int j = c + ch;
            bool ok = j < deg;
            int2 e = ebuf[beg + (ok ? j : (deg - 1))];
            if (!ok) e.y = 0;
            seW[wv][half * 32 + ch] = e;
        }
        for (int s0 = 0; s0 < nsl; s0 += 16) {
#pragma unroll
            for (int i = 0; i < 16; ++i) {
                int2 rec = seW[wv][half * 32 + s0 + i];   // broadcast ds_read_b64
                float w = __int_as_float(rec.y);
                unsigned v = *(const unsigned*)(hbase + ((unsigned)rec.x + chB));
                aL[i & 3] = fmaf(w, __uint_as_float(v << 16), aL[i & 3]);
                aH[i & 3] = fmaf(w, __uint_as_float(v & 0xFFFF0000u), aH[i & 3]);
            }
        }
    }
    float accL = (aL[0] + aL[1]) + (aL[2] + aL[3]);
    float accH = (aH[0] + aH[1]) + (aH[2] + aH[3]);

    // stage agg pairs (k 0..63) in fragment order
    int m = wv * 2 + half;                     // row 0..15
    int t = ch >> 4, q = (ch >> 2) & 3, jj = ch & 3;
    unsigned pack = ((unsigned)f2bf(accH) << 16) | (unsigned)f2bf(accL);
    AstW[t * 256 + (q * 16 + m) * 4 + jj] = pack;
    __syncthreads();

    if (wv < 4) {
        int quad = lane >> 4, m16 = lane & 15;
        int n = wv * 16 + m16;
        f32x4 cacc = {0.f, 0.f, 0.f, 0.f};
#pragma unroll
        for (int t2 = 0; t2 < 2; ++t2) {
            bf16x8 a = *(const bf16x8*)&AstW[t2 * 256 + lane * 4];
            cacc = __builtin_amdgcn_mfma_f32_16x16x32_bf16(a, bfrag[t2], cacc, 0, 0, 0);
        }
        cacc = __builtin_amdgcn_mfma_f32_16x16x32_bf16(aroot[0], bfrag[2], cacc, 0, 0, 0);
        cacc = __builtin_amdgcn_mfma_f32_16x16x32_bf16(aroot[1], bfrag[3], cacc, 0, 0, 0);
#pragma unroll
        for (int reg = 0; reg < 4; ++reg) {
            int row = quad * 4 + reg;
            size_t onode = (size_t)base + row;
            float v2 = cacc[reg] + bias;
            if (RELU) v2 = fmaxf(v2, 0.f);
            if (OUT32) ((float*)outp)[onode * DD + n] = v2;
            else       ((unsigned short*)outp)[onode * DD + n] = f2bf(v2);
        }
    }
}

extern "C" void kernel_launch(void* const* d_in, const int* in_sizes, int n_in,
                              void* d_out, int out_size, void* d_ws, size_t ws_size,
                              hipStream_t stream)
{
    const float* x     = (const float*)d_in[0];
    const int*   ei    = (const int*)d_in[1];
    const float* w     = (const float*)d_in[2];
    const float* Wrel1 = (const float*)d_in[4];
    const float* brel1 = (const float*)d_in[5];
    const float* Wroot1= (const float*)d_in[6];
    const float* Wrel2 = (const float*)d_in[7];
    const float* brel2 = (const float*)d_in[8];
    const float* Wroot2= (const float*)d_in[9];
    const float* Wrel3 = (const float*)d_in[10];
    const float* brel3 = (const float*)d_in[11];
    const float* Wroot3= (const float*)d_in[12];

    float* out = (float*)d_out;

    // workspace: ebuf | ecoarse (UN-aliased: copy overlaps p2) | xb | hb1 |
    //            hb2 | rowp | gcur | Bp   (~65 MB of 268)
    char* ws = (char*)d_ws;
    int2*  ebuf    = (int2*)ws;                ws += (size_t)NRANGE * RCAP * 8;  // 12.85 MB
    int2*  ecoarse = (int2*)ws;                ws += (size_t)NRANGE * RCAP * 8;  // 12.85 MB
    unsigned short* xb  = (unsigned short*)ws; ws += (size_t)NPAD * DD * 2;      // 12.85 MB
    unsigned short* hb1 = (unsigned short*)ws; ws += (size_t)NPAD * DD * 2;
    unsigned short* hb2 = (unsigned short*)ws; ws += (size_t)NPAD * DD * 2;
    int*   rowp  = (int*)ws;                   ws += (size_t)(NRANGE * RPSTRIDE + 16) * 4;
    int*   gcur  = (int*)ws;                   ws += (size_t)256 * 4;
    unsigned short* Bp = (unsigned short*)ws;  // 3 * 16 KB

    const int* src = ei;
    const int* dst = ei + NE;

    // ---- build: gcur init (bpack blk 3) -> bin -> place+copy (merged) ----
    bpack_kernel<<<4, 256, 0, stream>>>(Wrel1, Wroot1, Wrel2, Wroot2,
                                        Wrel3, Wroot3, Bp, gcur);
    p1_bin_kernel<<<625, 512, 0, stream>>>(src, dst, w, gcur, ecoarse);
    p2copy_kernel<<<NRANGE + CPBLK, 1024, 0, stream>>>(ecoarse, gcur, rowp,
                                                       ebuf, x, xb);

    // ---- 3 fused layers (ping-pong xb -> hb1 -> hb2 -> out) ----
    fused_layer_kernel<true, false><<<NN / 16, 512, 0, stream>>>(
        xb, rowp, ebuf, Bp, brel1, hb1);
    fused_layer_kernel<true, false><<<NN / 16, 512, 0, stream>>>(
        hb1, rowp, ebuf, Bp + (size_t)4 * 256 * 8, brel2, hb2);
    fused_layer_kernel<false, true><<<NN / 16, 512, 0, stream>>>(
        hb2, rowp, ebuf, Bp + (size_t)8 * 256 * 8, brel3, out);
}

// Round 15
// 253.415 us; speedup vs baseline: 1.0941x; 1.0136x over previous
//
#include <hip/hip_runtime.h>
#include <hip/hip_bf16.h>

#define NN 100000
#define NE 1280000
#define DD 64
#define RSHIFT 9             // 512-node dst ranges
#define NRANGE 196           // ceil(NN/512)
#define NPAD (NRANGE * 512)  // 100352
#define RCAP 8192            // fixed edge-slot capacity per range (mean 6554, 20 sigma)
#define RPSTRIDE 513         // rowp stride per range (512 cursors + end sentinel)

typedef __attribute__((ext_vector_type(8))) short bf16x8;
typedef __attribute__((ext_vector_type(4))) float f32x4;

static __device__ __forceinline__ unsigned short f2bf(float f) {
    __hip_bfloat16 h = __float2bfloat16(f);
    return *reinterpret_cast<unsigned short*>(&h);
}

// ---------------------------------------------------------------------------
// x (fp32) -> bf16 copy. Grid 6250 x 256, 4 elems/thread (exact: 6.4M).
// (Kept as its OWN dispatch: merging it into p1 (r12, +5.3us) or p2 (r14,
// +7.2us) both regressed -- the BW burst stretches the latency-bound build
// kernel's critical path.)
// ---------------------------------------------------------------------------
__global__ __launch_bounds__(256) void f32_to_bf16_kernel(
    const float* __restrict__ in, unsigned short* __restrict__ out)
{
    int i = (blockIdx.x * 256 + threadIdx.x) * 4;
    float4 v = *(const float4*)(in + i);
    ushort4 o;
    o.x = f2bf(v.x); o.y = f2bf(v.y); o.z = f2bf(v.z); o.w = f2bf(v.w);
    *(ushort4*)(out + i) = o;
}

// ---------------------------------------------------------------------------
// B-fragment pre-pack (blocks 0-2) + gcur fixed-base init (block 3). Grid 4.
// ---------------------------------------------------------------------------
__global__ __launch_bounds__(256) void bpack_kernel(
    const float* __restrict__ Wrel1, const float* __restrict__ Wroot1,
    const float* __restrict__ Wrel2, const float* __restrict__ Wroot2,
    const float* __restrict__ Wrel3, const float* __restrict__ Wroot3,
    unsigned short* __restrict__ Bp, int* __restrict__ gcur)
{
    int L = blockIdx.x;
    int tid = threadIdx.x;
    if (L == 3) {                         // gcur[r] = r*RCAP
        if (tid < NRANGE) gcur[tid] = tid * RCAP;
        return;
    }
    const float* Wrel  = (L == 0) ? Wrel1  : (L == 1) ? Wrel2  : Wrel3;
    const float* Wroot = (L == 0) ? Wroot1 : (L == 1) ? Wroot2 : Wroot3;
    int wv = tid >> 6, lane = tid & 63, quad = lane >> 4, m16 = lane & 15;
    int n = wv * 16 + m16;
    unsigned short* o = Bp + (size_t)L * 4 * 256 * 8;
#pragma unroll
    for (int t = 0; t < 4; ++t)
#pragma unroll
        for (int j = 0; j < 8; ++j) {
            int k = t * 32 + quad * 8 + j;
            float wval = (k < 64) ? Wrel[k * 64 + n] : Wroot[(k - 64) * 64 + n];
            o[((size_t)t * 256 + tid) * 8 + j] = f2bf(wval);
        }
}

// ---------------------------------------------------------------------------
// P1: bin edges by 512-node dst range into FIXED-CAPACITY segments.
// 512 thr, 4 edges/thr (2048-edge chunks, grid 625), wave-shfl scan over
// 196 bins. Record: src(17b)|local-dst(9b@17).
// ---------------------------------------------------------------------------
__global__ __launch_bounds__(512) void p1_bin_kernel(
    const int* __restrict__ src, const int* __restrict__ dst,
    const float* __restrict__ w, int* __restrict__ gcur,
    int2* __restrict__ ecoarse)
{
    __shared__ int2 stage[2048];                 // 16 KB
    __shared__ unsigned char sbkt[2048];         // 2 KB
    __shared__ int cnt[NRANGE], ofs[NRANGE], gpos[NRANGE];
    __shared__ int wsum[4];

    int tid = threadIdx.x;
    int e0 = blockIdx.x * 2048 + tid * 4;
    int4   s4 = *(const int4*)(src + e0);
    int4   d4 = *(const int4*)(dst + e0);
    float4 w4 = *(const float4*)(w + e0);

    if (tid < NRANGE) cnt[tid] = 0;
    __syncthreads();

    int ss[4] = {s4.x, s4.y, s4.z, s4.w};
    int dd[4] = {d4.x, d4.y, d4.z, d4.w};
    float ww[4] = {w4.x, w4.y, w4.z, w4.w};
    int b[4], p[4];
#pragma unroll
    for (int i = 0; i < 4; ++i) {
        b[i] = dd[i] >> RSHIFT;
        p[i] = atomicAdd(&cnt[b[i]], 1);
    }
    __syncthreads();

    int sum = 0, v = 0;
    if (tid < NRANGE) {
        v = cnt[tid];
        int lane6 = tid & 63;
        sum = v;
#pragma unroll
        for (int o = 1; o < 64; o <<= 1) {
            int t = __shfl_up(sum, o);
            if (lane6 >= o) sum += t;
        }
        if (lane6 == 63 || tid == NRANGE - 1) wsum[tid >> 6] = sum;
        ofs[tid] = sum - v;
    }
    __syncthreads();
    if (tid < NRANGE) {
        int wid = tid >> 6;
        int pre = 0;
#pragma unroll
        for (int k = 0; k < 3; ++k) pre += (k < wid) ? wsum[k] : 0;
        ofs[tid] += pre;
        if (v > 0) gpos[tid] = atomicAdd(&gcur[tid], v);
    }
    __syncthreads();

#pragma unroll
    for (int i = 0; i < 4; ++i) {
        int slot = ofs[b[i]] + p[i];
        stage[slot] = make_int2(ss[i] | ((dd[i] & 511) << 17), __float_as_int(ww[i]));
        sbkt[slot] = (unsigned char)b[i];
    }
    __syncthreads();

#pragma unroll
    for (int u = 0; u < 4; ++u) {
        int j = tid + u * 512;
        int bb = sbkt[j];
        ecoarse[gpos[bb] + (j - ofs[bb])] = stage[j];
    }
}

// ---------------------------------------------------------------------------
// P2: per-range count + wave-shfl scan -> rowp (stride-513, end sentinel) +
// cursors, then place. Grid NRANGE(196) x 1024 thr. beg = r*RCAP (fixed),
// end = gcur[r] (from p1). Final ebuf record: { src*128 (byte offset), w }.
// ---------------------------------------------------------------------------
__global__ __launch_bounds__(1024) void p2_place_kernel(
    const int2* __restrict__ ecoarse, const int* __restrict__ gcur,
    int* __restrict__ rowp, int2* __restrict__ ebuf)
{
    __shared__ int cnt[512];
    __shared__ int wsum[8];
    int r = blockIdx.x, tid = threadIdx.x;
    int beg = r * RCAP;
    int end = gcur[r];

    if (tid < 512) cnt[tid] = 0;
    __syncthreads();

    for (int j = beg + tid; j < end; j += 1024) {
        int2 rec = ecoarse[j];
        atomicAdd(&cnt[(rec.x >> 17) & 511], 1);
    }
    __syncthreads();

    int v = 0, sum = 0;
    if (tid < 512) {
        v = cnt[tid]; sum = v;
        int lane6 = tid & 63;
#pragma unroll
        for (int o = 1; o < 64; o <<= 1) {
            int t = __shfl_up(sum, o);
            if (lane6 >= o) sum += t;
        }
        if (lane6 == 63) wsum[tid >> 6] = sum;
    }
    __syncthreads();
    if (tid < 512) {
        int wid = tid >> 6;
        int pre = 0;
#pragma unroll
        for (int k = 0; k < 7; ++k) pre += (k < wid) ? wsum[k] : 0;
        int ex = beg + pre + sum - v;       // exclusive cursor for local node tid
        rowp[r * RPSTRIDE + tid] = ex;
        cnt[tid] = ex;
    }
    if (tid == 0) rowp[r * RPSTRIDE + 512] = end;   // range end sentinel
    __syncthreads();

    for (int j = beg + tid; j < end; j += 1024) {
        int2 rec = ecoarse[j];
        int dl = (rec.x >> 17) & 511;
        int pp = atomicAdd(&cnt[dl], 1);
        ebuf[pp] = make_int2((rec.x & 0x1FFFF) << 7, rec.y);   // src*128 bytes
    }
}

// ---------------------------------------------------------------------------
// FUSED layer (2-GROUP SEQUENTIAL): CSR gather + dual GEMM + bias (+ReLU).
// Block = 512 thr = 8 waves; processes TWO 16-node groups SEQUENTIALLY
// (base = blockIdx*32 + gi*16). Unlike the failed r13 paired loop, each
// group runs its own deg loop (zero padding tax); gains: B-frag/bias/rowp
// setup amortized over 2 groups, half the blocks, and after group A's
// barrier waves 4-7 start group B's gather while waves 0-3 run group A's
// GEMM (AstW double-buffered). Per-group body is the r12/r14-verified
// 41.6us kernel: half-wave per node, per-wave LDS record slab (pad w=0 at
// stage), half-uniform ds_read_b64 stream, pre-scaled byte row offsets,
// 16 row loads in flight/wave; agg k0..63 via AstW, root k64..127 direct
// from hb (kstep t2 in {2,3} = 16 B of row (base+m16) @ (t2-2)*64+quad*16).
// rowp stride-513 per range: idx = node + (node>>9).
// ---------------------------------------------------------------------------
template <bool RELU, bool OUT32>
__global__ __launch_bounds__(512) void fused_layer_kernel(
    const unsigned short* __restrict__ hb,   // input node table (gather + root)
    const int* __restrict__ rowp,
    const int2* __restrict__ ebuf,
    const unsigned short* __restrict__ Bp,   // [4][256][8] bf16 (this layer)
    const float* __restrict__ brel,
    void* __restrict__ outp)
{
    __shared__ __align__(16) unsigned int AstW[2][2 * 256];  // 4 KB (dbuf agg)
    __shared__ __align__(16) int2 seW[8][64];                // 4 KB per-wave slabs

    int tid = threadIdx.x;
    int lane = tid & 63;
    int wv = tid >> 6;            // 0..7
    int half = lane >> 5;         // node parity within wave
    int ch = lane & 31;           // channel pair
    int quad = lane >> 4, m16 = lane & 15;

    const char* __restrict__ hbase = (const char*)hb;
    unsigned chB = (unsigned)ch * 4;

    // B fragments + bias loaded ONCE for both groups (waves 0-3 only)
    bf16x8 bfrag[4];
    float bias = 0.f;
    if (wv < 4) {
#pragma unroll
        for (int t2 = 0; t2 < 4; ++t2)
            bfrag[t2] = *(const bf16x8*)(Bp + ((size_t)t2 * 256 + tid) * 8);
        bias = brel[(wv << 4) | m16];
    }

#pragma unroll
    for (int gi = 0; gi < 2; ++gi) {
        int base = blockIdx.x * 32 + gi * 16;
        int node = base + wv * 2 + half;
        int rr = base >> 9;       // range id (uniform per group)

        // direct root fragments for this group (waves 0-3), issued early
        bf16x8 aroot0, aroot1;
        if (wv < 4) {
            const char* rrow = hbase + (size_t)(base + m16) * 128 + quad * 16;
            aroot0 = *(const bf16x8*)(rrow);
            aroot1 = *(const bf16x8*)(rrow + 64);
        }

        int beg = rowp[node + rr];
        int end = rowp[node + rr + 1];
        int deg = end - beg;

        float aL[4] = {0.f, 0.f, 0.f, 0.f};
        float aH[4] = {0.f, 0.f, 0.f, 0.f};

        for (int c = 0; c < deg; c += 32) {
            int nsl = deg - c; if (nsl > 32) nsl = 32;
            // stage chunk records; pad slots get w=0 (one select per chunk)
            {
                int j = c + ch;
                bool ok = j < deg;
                int2 e = ebuf[beg + (ok ? j : (deg - 1))];
                if (!ok) e.y = 0;
                seW[wv][half * 32 + ch] = e;
            }
            for (int s0 = 0; s0 < nsl; s0 += 16) {
#pragma unroll
                for (int i = 0; i < 16; ++i) {
                    int2 rec = seW[wv][half * 32 + s0 + i];  // broadcast ds_read_b64
                    float w = __int_as_float(rec.y);
                    unsigned v = *(const unsigned*)(hbase + ((unsigned)rec.x + chB));
                    aL[i & 3] = fmaf(w, __uint_as_float(v << 16), aL[i & 3]);
                    aH[i & 3] = fmaf(w, __uint_as_float(v & 0xFFFF0000u), aH[i & 3]);
                }
            }
        }
        float accL = (aL[0] + aL[1]) + (aL[2] + aL[3]);
        float accH = (aH[0] + aH[1]) + (aH[2] + aH[3]);

        // stage agg pairs (k 0..63) in fragment order
        int m = wv * 2 + half;                     // row 0..15
        int t = ch >> 4, q = (ch >> 2) & 3, jj = ch & 3;
        unsigned pack = ((unsigned)f2bf(accH) << 16) | (unsigned)f2bf(accL);
        AstW[gi][t * 256 + (q * 16 + m) * 4 + jj] = pack;
        __syncthreads();
        // waves 4-7 fall through to group B's gather immediately;
        // waves 0-3 do group A's GEMM first (AstW double-buffered).

        if (wv < 4) {
            int n = wv * 16 + m16;
            f32x4 cacc = {0.f, 0.f, 0.f, 0.f};
#pragma unroll
            for (int t2 = 0; t2 < 2; ++t2) {
                bf16x8 a = *(const bf16x8*)&AstW[gi][t2 * 256 + lane * 4];
                cacc = __builtin_amdgcn_mfma_f32_16x16x32_bf16(a, bfrag[t2], cacc, 0, 0, 0);
            }
            cacc = __builtin_amdgcn_mfma_f32_16x16x32_bf16(aroot0, bfrag[2], cacc, 0, 0, 0);
            cacc = __builtin_amdgcn_mfma_f32_16x16x32_bf16(aroot1, bfrag[3], cacc, 0, 0, 0);
#pragma unroll
            for (int reg = 0; reg < 4; ++reg) {
                int row = quad * 4 + reg;
                size_t onode = (size_t)base + row;
                float v2 = cacc[reg] + bias;
                if (RELU) v2 = fmaxf(v2, 0.f);
                if (OUT32) ((float*)outp)[onode * DD + n] = v2;
                else       ((unsigned short*)outp)[onode * DD + n] = f2bf(v2);
            }
        }
    }
}

extern "C" void kernel_launch(void* const* d_in, const int* in_sizes, int n_in,
                              void* d_out, int out_size, void* d_ws, size_t ws_size,
                              hipStream_t stream)
{
    const float* x     = (const float*)d_in[0];
    const int*   ei    = (const int*)d_in[1];
    const float* w     = (const float*)d_in[2];
    const float* Wrel1 = (const float*)d_in[4];
    const float* brel1 = (const float*)d_in[5];
    const float* Wroot1= (const float*)d_in[6];
    const float* Wrel2 = (const float*)d_in[7];
    const float* brel2 = (const float*)d_in[8];
    const float* Wroot2= (const float*)d_in[9];
    const float* Wrel3 = (const float*)d_in[10];
    const float* brel3 = (const float*)d_in[11];
    const float* Wroot3= (const float*)d_in[12];

    float* out = (float*)d_out;

    // workspace: ebuf | ecoarse->xb alias | hb1 | hb2 | rowp | gcur | Bp
    char* ws = (char*)d_ws;
    int2*  ebuf    = (int2*)ws;                ws += (size_t)NRANGE * RCAP * 8;  // 12.85 MB
    int2*  ecoarse = (int2*)ws;                                                 // aliases xb
    unsigned short* xb  = (unsigned short*)ws; ws += (size_t)NRANGE * RCAP * 8;  // 12.85 MB (>= xb)
    unsigned short* hb1 = (unsigned short*)ws; ws += (size_t)NPAD * DD * 2;
    unsigned short* hb2 = (unsigned short*)ws; ws += (size_t)NPAD * DD * 2;
    int*   rowp  = (int*)ws;                   ws += (size_t)(NRANGE * RPSTRIDE + 16) * 4;
    int*   gcur  = (int*)ws;                   ws += (size_t)256 * 4;
    unsigned short* Bp = (unsigned short*)ws;  // 3 * 16 KB

    const int* src = ei;
    const int* dst = ei + NE;

    // ---- build (r11-verified arrangement): bpack -> bin -> place -> copy ---
    bpack_kernel<<<4, 256, 0, stream>>>(Wrel1, Wroot1, Wrel2, Wroot2,
                                        Wrel3, Wroot3, Bp, gcur);
    p1_bin_kernel<<<625, 512, 0, stream>>>(src, dst, w, gcur, ecoarse);
    p2_place_kernel<<<NRANGE, 1024, 0, stream>>>(ecoarse, gcur, rowp, ebuf);

    // ---- xb = bf16(x) (ecoarse dead now) ----
    f32_to_bf16_kernel<<<6250, 256, 0, stream>>>(x, xb);

    // ---- 3 fused 2-group layers (ping-pong xb -> hb1 -> hb2 -> out) ----
    fused_layer_kernel<true, false><<<NN / 32, 512, 0, stream>>>(
        xb, rowp, ebuf, Bp, brel1, hb1);
    fused_layer_kernel<true, false><<<NN / 32, 512, 0, stream>>>(
        hb1, rowp, ebuf, Bp + (size_t)4 * 256 * 8, brel2, hb2);
    fused_layer_kernel<false, true><<<NN / 32, 512, 0, stream>>>(
        hb2, rowp, ebuf, Bp + (size_t)8 * 256 * 8, brel3, out);
}